// Round 1
// baseline (426.222 us; speedup 1.0000x reference)
//
#include <hip/hip_runtime.h>

// Bilinear warp (grid_sample, zeros padding) of frame_t (8,64,256,256) fp32
// by flow_field (8,2,256,256) fp32.
// Math: reference's normalize->denormalize chain collapses to
//   ix = px + 0.5*flow_x ; iy = py + 0.5*flow_y
// One thread per spatial pixel (b,y,x); weights/offsets computed once and
// reused across all 64 channels. Block of 256 threads = one image row ->
// coalesced flow reads and output stores.

#define W_ 256
#define H_ 256
#define C_ 64
#define HW_ (H_ * W_)

__global__ __launch_bounds__(256) void warp_bilinear_kernel(
    const float* __restrict__ frame,   // (8,64,256,256)
    const float* __restrict__ flow,    // (8,2,256,256)
    float* __restrict__ out)           // (8,64,256,256)
{
    const int px = threadIdx.x;        // 0..255 (== W)
    const int by = blockIdx.x;         // b*H + y
    const int b  = by >> 8;
    const int py = by & 255;

    const int sp = py * W_ + px;

    const float fx = flow[(b * 2 + 0) * HW_ + sp];
    const float fy = flow[(b * 2 + 1) * HW_ + sp];

    const float ix = (float)px + 0.5f * fx;
    const float iy = (float)py + 0.5f * fy;

    const float ix0f = floorf(ix);
    const float iy0f = floorf(iy);
    const float wx1 = ix - ix0f;
    const float wx0 = 1.0f - wx1;
    const float wy1 = iy - iy0f;
    const float wy0 = 1.0f - wy1;

    const int ix0 = (int)ix0f;
    const int iy0 = (int)iy0f;
    const int ix1 = ix0 + 1;
    const int iy1 = iy0 + 1;

    const float vx0 = (ix0 >= 0 && ix0 < W_) ? 1.0f : 0.0f;
    const float vx1 = (ix1 >= 0 && ix1 < W_) ? 1.0f : 0.0f;
    const float vy0 = (iy0 >= 0 && iy0 < H_) ? 1.0f : 0.0f;
    const float vy1 = (iy1 >= 0 && iy1 < H_) ? 1.0f : 0.0f;

    const int xc0 = min(max(ix0, 0), W_ - 1);
    const int xc1 = min(max(ix1, 0), W_ - 1);
    const int yc0 = min(max(iy0, 0), H_ - 1);
    const int yc1 = min(max(iy1, 0), H_ - 1);

    const float w00 = wy0 * wx0 * vy0 * vx0;
    const float w01 = wy0 * wx1 * vy0 * vx1;
    const float w10 = wy1 * wx0 * vy1 * vx0;
    const float w11 = wy1 * wx1 * vy1 * vx1;

    const int o00 = yc0 * W_ + xc0;
    const int o01 = yc0 * W_ + xc1;
    const int o10 = yc1 * W_ + xc0;
    const int o11 = yc1 * W_ + xc1;

    const float* __restrict__ src = frame + (size_t)b * C_ * HW_;
    float* __restrict__ dst = out + (size_t)b * C_ * HW_ + sp;

#pragma unroll 8
    for (int c = 0; c < C_; ++c) {
        const float* __restrict__ p = src + c * HW_;
        const float v = w00 * p[o00] + w01 * p[o01] +
                        w10 * p[o10] + w11 * p[o11];
        dst[c * HW_] = v;
    }
}

extern "C" void kernel_launch(void* const* d_in, const int* in_sizes, int n_in,
                              void* d_out, int out_size, void* d_ws, size_t ws_size,
                              hipStream_t stream) {
    const float* frame = (const float*)d_in[0];
    const float* flow  = (const float*)d_in[1];
    float* out = (float*)d_out;

    const int N = 8;
    dim3 grid(N * H_);   // 2048 blocks: (b, y)
    dim3 block(W_);      // 256 threads: x
    warp_bilinear_kernel<<<grid, block, 0, stream>>>(frame, flow, out);
}

// Round 2
// 374.955 us; speedup vs baseline: 1.1367x; 1.1367x over previous
//
#include <hip/hip_runtime.h>

// Bilinear warp (grid_sample, zeros padding) of frame_t (8,64,256,256) fp32
// by flow_field (8,2,256,256) fp32.
//   ix = px + 0.5*flow_x ; iy = py + 0.5*flow_y   (normalization collapses)
//
// R2 structure:
//  - blockIdx % 8 = batch  -> each XCD (round-robin dealt) owns one batch
//    image, so the gather halo (±~21 rows) stays in that XCD's 4 MiB L2.
//  - 8 channels per block ("chunk"), chunk-major dispatch: per-XCD live
//    working set ~ (64 rows in flight + 42 halo) * 8ch * 1KB ~ 0.9 MB << L2.
//  - non-temporal output stores: don't let the streaming write allocate in
//    L2 and evict the gather window.

#define W_ 256
#define H_ 256
#define C_ 64
#define HW_ (H_ * W_)
#define CCHUNK 8
#define NCHUNK (C_ / CCHUNK)

__global__ __launch_bounds__(256) void warp_bilinear_kernel(
    const float* __restrict__ frame,   // (8,64,256,256)
    const float* __restrict__ flow,    // (8,2,256,256)
    float* __restrict__ out)           // (8,64,256,256)
{
    const int blk = blockIdx.x;
    const int b     = blk & 7;          // batch == XCD (round-robin heuristic)
    const int t     = blk >> 3;
    const int py    = t & 255;          // row
    const int chunk = t >> 8;           // 0..7, chunk-major (slowest)

    const int px = threadIdx.x;         // 0..255 == x
    const int sp = py * W_ + px;

    const float fx = flow[(b * 2 + 0) * HW_ + sp];
    const float fy = flow[(b * 2 + 1) * HW_ + sp];

    const float ix = (float)px + 0.5f * fx;
    const float iy = (float)py + 0.5f * fy;

    const float ix0f = floorf(ix);
    const float iy0f = floorf(iy);
    const float wx1 = ix - ix0f;
    const float wx0 = 1.0f - wx1;
    const float wy1 = iy - iy0f;
    const float wy0 = 1.0f - wy1;

    const int ix0 = (int)ix0f;
    const int iy0 = (int)iy0f;
    const int ix1 = ix0 + 1;
    const int iy1 = iy0 + 1;

    const float vx0 = (ix0 >= 0 && ix0 < W_) ? 1.0f : 0.0f;
    const float vx1 = (ix1 >= 0 && ix1 < W_) ? 1.0f : 0.0f;
    const float vy0 = (iy0 >= 0 && iy0 < H_) ? 1.0f : 0.0f;
    const float vy1 = (iy1 >= 0 && iy1 < H_) ? 1.0f : 0.0f;

    const int xc0 = min(max(ix0, 0), W_ - 1);
    const int xc1 = min(max(ix1, 0), W_ - 1);
    const int yc0 = min(max(iy0, 0), H_ - 1);
    const int yc1 = min(max(iy1, 0), H_ - 1);

    const float w00 = wy0 * wx0 * vy0 * vx0;
    const float w01 = wy0 * wx1 * vy0 * vx1;
    const float w10 = wy1 * wx0 * vy1 * vx0;
    const float w11 = wy1 * wx1 * vy1 * vx1;

    const int o00 = yc0 * W_ + xc0;
    const int o01 = yc0 * W_ + xc1;
    const int o10 = yc1 * W_ + xc0;
    const int o11 = yc1 * W_ + xc1;

    const size_t cbase = ((size_t)b * C_ + (size_t)chunk * CCHUNK) * HW_;
    const float* __restrict__ src = frame + cbase;
    float* __restrict__ dst = out + cbase + sp;

#pragma unroll
    for (int c = 0; c < CCHUNK; ++c) {
        const float* __restrict__ p = src + c * HW_;
        const float v = w00 * p[o00] + w01 * p[o01] +
                        w10 * p[o10] + w11 * p[o11];
        __builtin_nontemporal_store(v, dst + c * HW_);
    }
}

extern "C" void kernel_launch(void* const* d_in, const int* in_sizes, int n_in,
                              void* d_out, int out_size, void* d_ws, size_t ws_size,
                              hipStream_t stream) {
    const float* frame = (const float*)d_in[0];
    const float* flow  = (const float*)d_in[1];
    float* out = (float*)d_out;

    const int N = 8;
    dim3 grid(N * H_ * NCHUNK);  // 16384 blocks: (chunk-major, y, b)
    dim3 block(W_);              // 256 threads: x
    warp_bilinear_kernel<<<grid, block, 0, stream>>>(frame, flow, out);
}

// Round 3
// 311.035 us; speedup vs baseline: 1.3703x; 1.2055x over previous
//
#include <hip/hip_runtime.h>

// Bilinear warp (grid_sample, zeros padding) of frame_t (8,64,256,256) fp32
// by flow_field (8,2,256,256) fp32.
//   ix = px + 0.5*flow_x ; iy = py + 0.5*flow_y   (normalization collapses)
//
// R3 structure — kill the scattered global gather (R2 was VMEM-transaction
// bound: ~64 cyc per divergent wave-load):
//  - block = (b, c, 16-row band). Stage a 64-row source window (band +/-24
//    halo, clamped) into 64 KB LDS with coalesced float4 loads.
//  - gather the 4 bilinear taps from LDS (ds_read_b32; jittered addresses,
//    ~2-4 way bank aliasing tolerable).
//  - |disp|>24 taps (essentially impossible for randn*4, but data-dependent)
//    fall back to a masked global load for correctness; execz makes it free.
//  - blockIdx: low 3 bits = b -> XCD-local image; band-fastest within
//    channel -> consecutive windows overlap 48/64 rows in L2; flow slice
//    (512 KB/image) stays L2-resident across all 64 channel passes.
//  - non-temporal output stores (streaming, don't pollute L2).

#define B_ 8
#define C_ 64
#define H_ 256
#define W_ 256
#define HW_ (H_ * W_)
#define BAND 16
#define NBAND (H_ / BAND)
#define HALO_LO 24
#define WROWS 64                       // HALO_LO + BAND + 24 rows above
#define WFLOATS (WROWS * W_)           // 16384 floats = 64 KiB

__global__ __launch_bounds__(256, 2) void warp_bilinear_kernel(
    const float* __restrict__ frame,   // (8,64,256,256)
    const float* __restrict__ flow,    // (8,2,256,256)
    float* __restrict__ out)           // (8,64,256,256)
{
    __shared__ float win[WFLOATS];

    const int blk  = blockIdx.x;
    const int b    = blk & 7;          // XCD-local batch
    const int t    = blk >> 3;
    const int band = t & (NBAND - 1);  // fastest: consecutive windows overlap
    const int c    = t >> 4;

    const int r0  = band * BAND;
    const int wlo = r0 - HALO_LO;      // first window row (may be <0)

    const int tid = threadIdx.x;       // 0..255
    const float* __restrict__ src = frame + ((size_t)(b * C_ + c)) * HW_;

    // ---- stage 64 rows x 256 cols into LDS, coalesced float4 ----
#pragma unroll
    for (int it = 0; it < WFLOATS / (256 * 4); ++it) {   // 16 iters
        const int lin = it * 1024 + tid * 4;             // float index in window
        const int wr  = lin >> 8;                        // window row
        const int wx  = lin & 255;
        const int gy  = min(max(wlo + wr, 0), H_ - 1);   // clamp (dups are L2 hits)
        const float4 v = *(const float4*)(src + gy * W_ + wx);
        *(float4*)(win + lin) = v;
    }
    __syncthreads();

    // ---- gather 16 band rows ----
    const int px = tid;
    float* __restrict__ dst = out + ((size_t)(b * C_ + c)) * HW_;
    const float* __restrict__ flx = flow + (size_t)(b * 2 + 0) * HW_;
    const float* __restrict__ fly = flow + (size_t)(b * 2 + 1) * HW_;

    for (int r = 0; r < BAND; ++r) {
        const int py = r0 + r;
        const int sp = py * W_ + px;

        const float fx = flx[sp];
        const float fy = fly[sp];

        const float ix = (float)px + 0.5f * fx;
        const float iy = (float)py + 0.5f * fy;

        const float ix0f = floorf(ix);
        const float iy0f = floorf(iy);
        const float wx1 = ix - ix0f;
        const float wx0 = 1.0f - wx1;
        const float wy1 = iy - iy0f;
        const float wy0 = 1.0f - wy1;

        const int ix0 = (int)ix0f;
        const int iy0 = (int)iy0f;
        const int ix1 = ix0 + 1;
        const int iy1 = iy0 + 1;

        const float vx0 = (ix0 >= 0 && ix0 < W_) ? 1.0f : 0.0f;
        const float vx1 = (ix1 >= 0 && ix1 < W_) ? 1.0f : 0.0f;
        const float vy0 = (iy0 >= 0 && iy0 < H_) ? 1.0f : 0.0f;
        const float vy1 = (iy1 >= 0 && iy1 < H_) ? 1.0f : 0.0f;

        const int xc0 = min(max(ix0, 0), W_ - 1);
        const int xc1 = min(max(ix1, 0), W_ - 1);
        const int yc0 = min(max(iy0, 0), H_ - 1);
        const int yc1 = min(max(iy1, 0), H_ - 1);

        const float w00 = wy0 * wx0 * vy0 * vx0;
        const float w01 = wy0 * wx1 * vy0 * vx1;
        const float w10 = wy1 * wx0 * vy1 * vx0;
        const float w11 = wy1 * wx1 * vy1 * vx1;

        // tap: LDS if the (clamped) row is inside the window, else rare
        // masked global fallback (execz-skipped when no lane needs it).
        auto tap = [&](int yc, int xc) -> float {
            const int wr = yc - wlo;
            if ((unsigned)wr < (unsigned)WROWS) {
                return win[wr * W_ + xc];
            }
            return src[yc * W_ + xc];
        };

        const float t00 = tap(yc0, xc0);
        const float t01 = tap(yc0, xc1);
        const float t10 = tap(yc1, xc0);
        const float t11 = tap(yc1, xc1);

        const float v = w00 * t00 + w01 * t01 + w10 * t10 + w11 * t11;
        __builtin_nontemporal_store(v, dst + sp);
    }
}

extern "C" void kernel_launch(void* const* d_in, const int* in_sizes, int n_in,
                              void* d_out, int out_size, void* d_ws, size_t ws_size,
                              hipStream_t stream) {
    const float* frame = (const float*)d_in[0];
    const float* flow  = (const float*)d_in[1];
    float* out = (float*)d_out;

    dim3 grid(B_ * C_ * NBAND);   // 8192 blocks: (c, band, b) with b fastest
    dim3 block(256);
    warp_bilinear_kernel<<<grid, block, 0, stream>>>(frame, flow, out);
}